// Round 2
// 303.199 us; speedup vs baseline: 1.0382x; 1.0382x over previous
//
#include <hip/hip_runtime.h>

#define T_STEPS 256
#define BATCH   128
#define DIM     1024
#define NROWS   (T_STEPS * BATCH)        // 32768 qx rows
#define TOTROWS (NROWS + 2 * BATCH)      // + hx, cx broadcast rows = 33024

typedef float vfloat4 __attribute__((ext_vector_type(4)));  // for nontemporal builtins

// ws float-offset layout
#define WS_M     0                        // float[4*1024]
#define WS_V     4096                     // float[4]
#define WS_CB    4128                     // float[4]
#define WS_ZERO_BYTES ((WS_CB + 4) * 4)   // memset covers M + v + cb
#define WS_QX    8192                     // float4[32768]

// ---------- prep (one kernel): M = Wq@Wi via fp32 HW atomics; v/cb via atomics ----------
__global__ __launch_bounds__(256) void k_prep(const float* __restrict__ Wi,
                                              const float* __restrict__ Wh,
                                              const float* __restrict__ bi,
                                              const float* __restrict__ bh,
                                              const float* __restrict__ Wq,
                                              float* __restrict__ M,
                                              float* __restrict__ v,
                                              float* __restrict__ cb) {
    int blk  = blockIdx.x;
    int tid  = threadIdx.x;
    int wave = tid >> 6;
    int lane = tid & 63;

    if (blk < 64) {
        // M partials: this block covers j in [blk*16, blk*16+16)
        int j0 = blk * 16;
        #pragma unroll
        for (int db = 0; db < 4; db++) {
            int d = db * 256 + tid;
            float a0 = 0.f, a1 = 0.f, a2 = 0.f, a3 = 0.f;
            #pragma unroll 4
            for (int jj = 0; jj < 16; jj++) {
                int j = j0 + jj;
                float wv = Wi[(size_t)j * DIM + d];   // coalesced 1KB/instr
                a0 += Wq[0 * DIM + j] * wv;           // uniform -> scalar loads
                a1 += Wq[1 * DIM + j] * wv;
                a2 += Wq[2 * DIM + j] * wv;
                a3 += Wq[3 * DIM + j] * wv;
            }
            unsafeAtomicAdd(&M[0 * DIM + d], a0);
            unsafeAtomicAdd(&M[1 * DIM + d], a1);
            unsafeAtomicAdd(&M[2 * DIM + d], a2);
            unsafeAtomicAdd(&M[3 * DIM + d], a3);
        }
    } else {
        // Wh rowsums -> v, cb contributions; each wave handles 4 rows
        int j0 = (blk - 64) * 16 + wave * 4;
        float sv0 = 0.f, sv1 = 0.f, sv2 = 0.f, sv3 = 0.f;
        float sc0 = 0.f, sc1 = 0.f, sc2 = 0.f, sc3 = 0.f;
        #pragma unroll
        for (int jj = 0; jj < 4; jj++) {
            int j = j0 + jj;
            const float4* row = (const float4*)(Wh + (size_t)j * DIM);
            float s = 0.f;
            #pragma unroll
            for (int k = 0; k < 4; k++) {
                float4 t4 = row[k * 64 + lane];
                s += t4.x + t4.y + t4.z + t4.w;
            }
            #pragma unroll
            for (int off = 32; off; off >>= 1) s += __shfl_xor(s, off, 64);
            float bb = bi[j] + bh[j];
            float q0 = Wq[0 * DIM + j], q1 = Wq[1 * DIM + j];
            float q2 = Wq[2 * DIM + j], q3 = Wq[3 * DIM + j];
            sv0 += q0 * s;  sc0 += q0 * bb;
            sv1 += q1 * s;  sc1 += q1 * bb;
            sv2 += q2 * s;  sc2 += q2 * bb;
            sv3 += q3 * s;  sc3 += q3 * bb;
        }
        if (lane == 0) {
            unsafeAtomicAdd(&v[0], sv0);  unsafeAtomicAdd(&v[1], sv1);
            unsafeAtomicAdd(&v[2], sv2);  unsafeAtomicAdd(&v[3], sv3);
            unsafeAtomicAdd(&cb[0], sc0); unsafeAtomicAdd(&cb[1], sc1);
            unsafeAtomicAdd(&cb[2], sc2); unsafeAtomicAdd(&cb[3], sc3);
        }
    }
}

// ---------- qx = inputs @ M.T  [T*B, 4] ; wave per row ----------
__global__ __launch_bounds__(256) void k_qx(const float* __restrict__ x,
                                            const float* __restrict__ M,
                                            float4* __restrict__ qx4) {
    int gtid   = blockIdx.x * blockDim.x + threadIdx.x;
    int wave   = gtid >> 6;
    int lane   = threadIdx.x & 63;
    int nwaves = (gridDim.x * blockDim.x) >> 6;

    float4 m[4][4];                                    // M fragment in regs
    #pragma unroll
    for (int w = 0; w < 4; w++)
        #pragma unroll
        for (int k = 0; k < 4; k++)
            m[w][k] = *(const float4*)(M + w * DIM + k * 256 + lane * 4);

    for (int r = wave; r < NROWS; r += nwaves) {
        const float4* row = (const float4*)(x + (size_t)r * DIM);
        float a0 = 0.f, a1 = 0.f, a2 = 0.f, a3 = 0.f;
        #pragma unroll
        for (int k = 0; k < 4; k++) {
            float4 xv = row[k * 64 + lane];            // contiguous 1 KB/instr
            a0 += xv.x * m[0][k].x + xv.y * m[0][k].y + xv.z * m[0][k].z + xv.w * m[0][k].w;
            a1 += xv.x * m[1][k].x + xv.y * m[1][k].y + xv.z * m[1][k].z + xv.w * m[1][k].w;
            a2 += xv.x * m[2][k].x + xv.y * m[2][k].y + xv.z * m[2][k].z + xv.w * m[2][k].w;
            a3 += xv.x * m[3][k].x + xv.y * m[3][k].y + xv.z * m[3][k].z + xv.w * m[3][k].w;
        }
        #pragma unroll
        for (int off = 32; off; off >>= 1) {
            a0 += __shfl_xor(a0, off, 64);
            a1 += __shfl_xor(a1, off, 64);
            a2 += __shfl_xor(a2, off, 64);
            a3 += __shfl_xor(a3, off, 64);
        }
        if (lane == 0) qx4[r] = make_float4(a0, a1, a2, a3);
    }
}

// ---------- recurrence + broadcast write, fused ----------
// One block per batch element b. All 4 waves redundantly compute the same
// serial chain (latency-bound; VALU idle anyway, so redundancy is free and
// needs no intra-block sync). Each wave stores its quarter of the 4 KB output
// row per step with one nontemporal float4 store, which hides under the
// transcendental dependency chain of the next step.
__device__ __forceinline__ float fast_tanh(float x) {
    float e = __expf(2.f * x);
    return (e - 1.f) * __builtin_amdgcn_rcpf(e + 1.f);
}

__device__ __forceinline__ void rec_step(float4 q,
                                         float b0, float b1, float b2, float b3,
                                         float v0, float v1, float v2, float v3,
                                         float& h, float& c) {
    float z0 = __cosf(q.x + b0 + h * v0);
    float z1 = __cosf(q.y + b1 + h * v1);
    float z2 = __cosf(q.z + b2 + h * v2);
    float z3 = __cosf(q.w + b3 + h * v3);
    float e1 = z0 * z1;
    float e2 = e1 * z2;
    float e3 = e2 * z3;
    float e0 = z1 * z2 * z3;
    float x0 = __expf(e0), x1 = __expf(e1), x2 = __expf(e2), x3 = __expf(e3);
    float inv = __builtin_amdgcn_rcpf(x0 + x1 + x2 + x3);
    float f  = x0 * inv;
    float i_ = x1 * inv;
    float g  = x2 * inv;
    float o  = x3 * inv;
    c = f * c + i_ * fast_tanh(g);
    h = o * fast_tanh(c);
}

__global__ __launch_bounds__(256) void k_recw(const float* __restrict__ bq,
                                              const float* __restrict__ theta,
                                              const float* __restrict__ v,
                                              const float* __restrict__ cbp,
                                              const float4* __restrict__ qx4,
                                              float* __restrict__ out) {
    const int b    = blockIdx.x;              // one chain per block
    const int wave = threadIdx.x >> 6;        // quarter-row this wave stores
    const int lane = threadIdx.x & 63;
    const int foff = wave * 256 + lane * 4;   // float offset within the 4 KB row

    float v0 = v[0], v1 = v[1], v2 = v[2], v3 = v[3];
    float b0 = cbp[0] + bq[0] + theta[0];
    float b1 = cbp[1] + bq[1] + theta[1];
    float b2 = cbp[2] + bq[2] + theta[2];
    float b3 = cbp[3] + bq[3] + theta[3];

    float h = 0.f, c = 0.f;

    // preload first 8 steps (same address across lanes -> broadcast loads, L2-hot)
    float4 q0 = qx4[0 * BATCH + b], q1 = qx4[1 * BATCH + b];
    float4 q2 = qx4[2 * BATCH + b], q3 = qx4[3 * BATCH + b];
    float4 q4 = qx4[4 * BATCH + b], q5 = qx4[5 * BATCH + b];
    float4 q6 = qx4[6 * BATCH + b], q7 = qx4[7 * BATCH + b];

    #define EMIT_H(tt)                                                          \
        do {                                                                    \
            vfloat4 vv = {h, h, h, h};                                          \
            __builtin_nontemporal_store(vv,                                     \
                (vfloat4*)(out + ((size_t)(tt) * BATCH + b) * DIM + foff));     \
        } while (0)

    for (int t = 0; t < T_STEPS; t += 8) {
        float4 n0, n1, n2, n3, n4, n5, n6, n7;
        if (t + 8 < T_STEPS) {                // prefetch next 8 (issued up front)
            n0 = qx4[(t + 8)  * BATCH + b];  n1 = qx4[(t + 9)  * BATCH + b];
            n2 = qx4[(t + 10) * BATCH + b];  n3 = qx4[(t + 11) * BATCH + b];
            n4 = qx4[(t + 12) * BATCH + b];  n5 = qx4[(t + 13) * BATCH + b];
            n6 = qx4[(t + 14) * BATCH + b];  n7 = qx4[(t + 15) * BATCH + b];
        }
        rec_step(q0, b0, b1, b2, b3, v0, v1, v2, v3, h, c); EMIT_H(t + 0);
        rec_step(q1, b0, b1, b2, b3, v0, v1, v2, v3, h, c); EMIT_H(t + 1);
        rec_step(q2, b0, b1, b2, b3, v0, v1, v2, v3, h, c); EMIT_H(t + 2);
        rec_step(q3, b0, b1, b2, b3, v0, v1, v2, v3, h, c); EMIT_H(t + 3);
        rec_step(q4, b0, b1, b2, b3, v0, v1, v2, v3, h, c); EMIT_H(t + 4);
        rec_step(q5, b0, b1, b2, b3, v0, v1, v2, v3, h, c); EMIT_H(t + 5);
        rec_step(q6, b0, b1, b2, b3, v0, v1, v2, v3, h, c); EMIT_H(t + 6);
        rec_step(q7, b0, b1, b2, b3, v0, v1, v2, v3, h, c); EMIT_H(t + 7);
        q0 = n0; q1 = n1; q2 = n2; q3 = n3; q4 = n4; q5 = n5; q6 = n6; q7 = n7;
    }
    #undef EMIT_H

    // tail rows: hx broadcast (row NROWS + b) = final h; cx broadcast = final c
    vfloat4 hv = {h, h, h, h};
    vfloat4 cv = {c, c, c, c};
    __builtin_nontemporal_store(hv,
        (vfloat4*)(out + ((size_t)NROWS + b) * DIM + foff));
    __builtin_nontemporal_store(cv,
        (vfloat4*)(out + ((size_t)NROWS + BATCH + b) * DIM + foff));
}

extern "C" void kernel_launch(void* const* d_in, const int* in_sizes, int n_in,
                              void* d_out, int out_size, void* d_ws, size_t ws_size,
                              hipStream_t stream) {
    const float* inputs = (const float*)d_in[0];
    const float* Wi     = (const float*)d_in[1];
    const float* bi     = (const float*)d_in[2];
    const float* Wh     = (const float*)d_in[3];
    const float* bh     = (const float*)d_in[4];
    const float* Wq     = (const float*)d_in[5];
    const float* bq     = (const float*)d_in[6];
    const float* theta  = (const float*)d_in[7];
    float* out = (float*)d_out;
    float* ws  = (float*)d_ws;

    float*  M    = ws + WS_M;
    float*  v    = ws + WS_V;
    float*  cb   = ws + WS_CB;
    float4* qx4  = (float4*)(ws + WS_QX);

    (void)hipMemsetAsync(ws, 0, WS_ZERO_BYTES, stream);    // zero M + v + cb
    k_prep <<<128,   256, 0, stream>>>(Wi, Wh, bi, bh, Wq, M, v, cb);
    k_qx   <<<1024,  256, 0, stream>>>(inputs, M, qx4);
    k_recw <<<BATCH, 256, 0, stream>>>(bq, theta, v, cb, qx4, out);
}